// Round 13
// baseline (139.371 us; speedup 1.0000x reference)
//
#include <hip/hip_runtime.h>
#include <math.h>

// CRF loss: B=256, L=256, T=50.
// R13: chunked matrix-product scan with COLUMN-SLAB parallelism.
//   normalizer = v0 . M1..M255 . 1,  M_l = mask_l ? E2*diag(eh_l) : I.
//   Scan kernel, 6656 blocks (1 wave each):
//     blocks 0..255    fwd vector chain  u = v0 . M1..M31     (R10-proven)
//     blocks 256..511  bwd vector chain  w = M224..M255 . 1   (R10-proven)
//     blocks 512..6655 middle chunk-slabs: (b, c=1..6, w=0..3):
//       Y = T_c[:, 16w..16w+15],  Y <- diag(eh_l)*E2^T*Y, 32 steps.
//       sigma K-permutation (R11-verified) makes the C-layout -> B-frag repack
//       lane-local AND column-local -> slabs are fully independent.
//       Per-slab renorm by own diagonal pivot Y[16w][16w]; S_w stored per slab.
//   Combine (256 blocks): per chunk, x_j *= 2^(S_w(j)-smax) then x <- T~_c*x
//       (coalesced col-major loads), renorm; finally dot w + gold.

#define TAGS 50
#define LEN 256
#define NB 256
#define VST 32
#define NCH 6
#define CST 32
#define INV_LN2 1.4426950408889634f
#define LN2 0.6931471805599453f

typedef __attribute__((ext_vector_type(8))) short bf16x8;
typedef __attribute__((ext_vector_type(4))) float f32x4;

#if __has_builtin(__builtin_amdgcn_exp2f)
#define EXP2F(x) __builtin_amdgcn_exp2f(x)
#else
#define EXP2F(x) exp2f(x)
#endif
#if __has_builtin(__builtin_amdgcn_logf)
#define LOG2F(x) __builtin_amdgcn_logf(x)
#else
#define LOG2F(x) log2f(x)
#endif
#if __has_builtin(__builtin_amdgcn_rcpf)
#define RCPF(x) __builtin_amdgcn_rcpf(x)
#else
#define RCPF(x) (1.0f / (x))
#endif

__device__ __forceinline__ float readlane_f(float v, int srclane) {
  return __builtin_bit_cast(float,
      __builtin_amdgcn_readlane(__builtin_bit_cast(int, v), srclane));
}

__device__ __forceinline__ int bfpack(float lo, float hi) {
  unsigned lb = __builtin_bit_cast(unsigned, lo) + 0x8000u;
  unsigned hb = __builtin_bit_cast(unsigned, hi) + 0x8000u;
#if __has_builtin(__builtin_amdgcn_perm)
  return (int)__builtin_amdgcn_perm(hb, lb, 0x07060302u);
#else
  return (int)((hb & 0xFFFF0000u) | (lb >> 16));
#endif
}

union U8 { int i[4]; bf16x8 v; };

// ws layout (floats)
#define WS_U(b)     ((b) * 64)
#define WS_W(b)     ((NB + (b)) * 64)
#define WS_SF(b)    (2 * NB * 64 + (b))
#define WS_SB(b)    (2 * NB * 64 + NB + (b))
#define WS_SC4(b,c) (2 * NB * 64 + 2 * NB + ((b) * NCH + (c)) * 4)
#define WS_T(b,c)   (2 * NB * 64 + 2 * NB + NB * NCH * 4 + (((b) * NCH + (c)) * 64) * 64)

__global__ __launch_bounds__(64) void crf_scan_kernel(
    const float* __restrict__ feats,   // (B, L, T)
    const float* __restrict__ trans,   // (T, T)
    const int*   __restrict__ mask,    // (B, L)
    float*       __restrict__ ws)
{
  const int bid  = blockIdx.x;
  const int lane = threadIdx.x;
  const int q    = lane >> 4;
  const int n    = lane & 15;
  const f32x4 zero4 = {0.0f, 0.0f, 0.0f, 0.0f};

  if (bid < 2 * NB) {
    // ================= VECTOR CHAINS (R10-proven machinery) =================
    const bool is_fwd = bid < NB;
    const int b = is_fwd ? bid : bid - NB;

    __shared__ __align__(16) float fl[VST * TAGS];
    __shared__ int ml[VST];

    const int base_l = is_fwd ? 0 : (LEN - VST);
    const float* fb = feats + ((size_t)b * LEN + base_l) * TAGS;
    const int*   mb = mask + b * LEN + base_l;

    {
      const float4* fv = (const float4*)fb;
      for (int i = lane; i < (VST * TAGS) / 4; i += 64) {
        float4 v4 = fv[i];
        v4.x *= INV_LN2; v4.y *= INV_LN2; v4.z *= INV_LN2; v4.w *= INV_LN2;
        *(float4*)&fl[i * 4] = v4;
      }
      for (int i = lane; i < VST; i += 64) ml[i] = mb[i];
    }

    int tcl[4], vld[4];
#pragma unroll
    for (int t = 0; t < 4; ++t) {
      const int tg = n + 16 * t;
      vld[t] = tg < TAGS;
      tcl[t] = vld[t] ? tg : (TAGS - 1);
    }

    U8 Bfr[4][2];
#pragma unroll
    for (int t = 0; t < 4; ++t)
#pragma unroll
      for (int c = 0; c < 2; ++c)
#pragma unroll
        for (int r = 0; r < 4; ++r) {
          const int col = 16 * t + n;
          const int tag0 = 16 * c + 4 * q + r;
          const int tag1 = tag0 + 32;
          float e0 = 0.0f, e1 = 0.0f;
          if (col < TAGS) {
            if (tag0 < TAGS)
              e0 = EXP2F((is_fwd ? trans[tag0 * TAGS + col]
                                 : trans[col * TAGS + tag0]) * INV_LN2);
            if (tag1 < TAGS)
              e1 = EXP2F((is_fwd ? trans[tag1 * TAGS + col]
                                 : trans[col * TAGS + tag1]) * INV_LN2);
          }
          Bfr[t][c].i[r] = bfpack(e0, e1);
        }

    int addr[4];
#pragma unroll
    for (int r = 0; r < 4; ++r) addr[r] = (4 * q + r) * 4;

    __syncthreads();

    float v[4], S;
    if (is_fwd) {
      const float c0 = fl[0];
#pragma unroll
      for (int t = 0; t < 4; ++t) v[t] = vld[t] ? EXP2F(fl[tcl[t]] - c0) : 0.0f;
      S = c0;
      float eh[4];
#pragma unroll
      for (int t = 0; t < 4; ++t) eh[t] = EXP2F(fl[TAGS + tcl[t]]);
      int m_nxt = ml[1];

      for (int l = 1; l < VST; ++l) {
        const int m_cur = m_nxt;
        const int ln = (l + 1 < VST) ? (l + 1) : (VST - 1);
        const int P0 = bfpack(v[0], v[2]);
        const int P1 = bfpack(v[1], v[3]);
        const float cc = readlane_f(v[0], 0);
        const float rr = RCPF(cc);
        U8 A0, A1;
#pragma unroll
        for (int r = 0; r < 4; ++r) {
          A0.i[r] = __builtin_amdgcn_ds_bpermute(addr[r], P0);
          A1.i[r] = __builtin_amdgcn_ds_bpermute(addr[r], P1);
        }
        f32x4 d0 = __builtin_amdgcn_mfma_f32_16x16x32_bf16(A0.v, Bfr[0][0].v, zero4, 0, 0, 0);
        f32x4 d1 = __builtin_amdgcn_mfma_f32_16x16x32_bf16(A0.v, Bfr[1][0].v, zero4, 0, 0, 0);
        f32x4 d2 = __builtin_amdgcn_mfma_f32_16x16x32_bf16(A0.v, Bfr[2][0].v, zero4, 0, 0, 0);
        f32x4 d3 = __builtin_amdgcn_mfma_f32_16x16x32_bf16(A0.v, Bfr[3][0].v, zero4, 0, 0, 0);
        f32x4 g0 = __builtin_amdgcn_mfma_f32_16x16x32_bf16(A1.v, Bfr[0][1].v, zero4, 0, 0, 0);
        f32x4 g1 = __builtin_amdgcn_mfma_f32_16x16x32_bf16(A1.v, Bfr[1][1].v, zero4, 0, 0, 0);
        f32x4 g2 = __builtin_amdgcn_mfma_f32_16x16x32_bf16(A1.v, Bfr[2][1].v, zero4, 0, 0, 0);
        f32x4 g3 = __builtin_amdgcn_mfma_f32_16x16x32_bf16(A1.v, Bfr[3][1].v, zero4, 0, 0, 0);
        float ehn[4];
#pragma unroll
        for (int t = 0; t < 4; ++t) ehn[t] = fl[ln * TAGS + tcl[t]];
        const int m_n2 = ml[ln];
        v[0] = ((m_cur > 0) ? (d0[0] + g0[0]) * eh[0] : v[0]) * rr;
        v[1] = ((m_cur > 0) ? (d1[0] + g1[0]) * eh[1] : v[1]) * rr;
        v[2] = ((m_cur > 0) ? (d2[0] + g2[0]) * eh[2] : v[2]) * rr;
        v[3] = ((m_cur > 0) ? (d3[0] + g3[0]) * eh[3] : v[3]) * rr;
        S += LOG2F(cc);
#pragma unroll
        for (int t = 0; t < 4; ++t) eh[t] = EXP2F(ehn[t]);
        m_nxt = m_n2;
      }
      if (lane < 16) {
#pragma unroll
        for (int t = 0; t < 4; ++t) ws[WS_U(b) + n + 16 * t] = v[t];
      }
      if (lane == 0) ws[WS_SF(b)] = S;
    } else {
#pragma unroll
      for (int t = 0; t < 4; ++t) v[t] = vld[t] ? 1.0f : 0.0f;
      S = 0.0f;
      float eh[4];
#pragma unroll
      for (int t = 0; t < 4; ++t) eh[t] = EXP2F(fl[(VST - 1) * TAGS + tcl[t]]);
      int m_nxt = ml[VST - 1];

      for (int l = VST - 1; l >= 0; --l) {
        const int m_cur = m_nxt;
        const int ln = (l > 0) ? (l - 1) : 0;
        const float x0 = v[0] * eh[0];
        const float x1 = v[1] * eh[1];
        const float x2 = v[2] * eh[2];
        const float x3 = v[3] * eh[3];
        const int P0 = bfpack(x0, x2);
        const int P1 = bfpack(x1, x3);
        const float cc = readlane_f(v[0], 0);
        const float rr = RCPF(cc);
        U8 A0, A1;
#pragma unroll
        for (int r = 0; r < 4; ++r) {
          A0.i[r] = __builtin_amdgcn_ds_bpermute(addr[r], P0);
          A1.i[r] = __builtin_amdgcn_ds_bpermute(addr[r], P1);
        }
        f32x4 d0 = __builtin_amdgcn_mfma_f32_16x16x32_bf16(A0.v, Bfr[0][0].v, zero4, 0, 0, 0);
        f32x4 d1 = __builtin_amdgcn_mfma_f32_16x16x32_bf16(A0.v, Bfr[1][0].v, zero4, 0, 0, 0);
        f32x4 d2 = __builtin_amdgcn_mfma_f32_16x16x32_bf16(A0.v, Bfr[2][0].v, zero4, 0, 0, 0);
        f32x4 d3 = __builtin_amdgcn_mfma_f32_16x16x32_bf16(A0.v, Bfr[3][0].v, zero4, 0, 0, 0);
        f32x4 g0 = __builtin_amdgcn_mfma_f32_16x16x32_bf16(A1.v, Bfr[0][1].v, zero4, 0, 0, 0);
        f32x4 g1 = __builtin_amdgcn_mfma_f32_16x16x32_bf16(A1.v, Bfr[1][1].v, zero4, 0, 0, 0);
        f32x4 g2 = __builtin_amdgcn_mfma_f32_16x16x32_bf16(A1.v, Bfr[2][1].v, zero4, 0, 0, 0);
        f32x4 g3 = __builtin_amdgcn_mfma_f32_16x16x32_bf16(A1.v, Bfr[3][1].v, zero4, 0, 0, 0);
        float ehn[4];
#pragma unroll
        for (int t = 0; t < 4; ++t) ehn[t] = fl[ln * TAGS + tcl[t]];
        const int m_n2 = ml[ln];
        v[0] = ((m_cur > 0) ? (d0[0] + g0[0]) : v[0]) * rr;
        v[1] = ((m_cur > 0) ? (d1[0] + g1[0]) : v[1]) * rr;
        v[2] = ((m_cur > 0) ? (d2[0] + g2[0]) : v[2]) * rr;
        v[3] = ((m_cur > 0) ? (d3[0] + g3[0]) : v[3]) * rr;
        S += LOG2F(cc);
#pragma unroll
        for (int t = 0; t < 4; ++t) eh[t] = EXP2F(ehn[t]);
        m_nxt = m_n2;
      }
      if (lane < 16) {
#pragma unroll
        for (int t = 0; t < 4; ++t) ws[WS_W(b) + n + 16 * t] = v[t];
      }
      if (lane == 0) ws[WS_SB(b)] = S;
    }
    return;
  }

  // =================== MIDDLE CHUNK COLUMN-SLABS ========================
  {
    const int i2 = bid - 2 * NB;
    const int b = i2 / (NCH * 4);
    const int rem = i2 - b * (NCH * 4);
    const int cidx = rem >> 2;                        // 0..5 -> chunk c = cidx+1
    const int w = rem & 3;                            // column slab: cols 16w..16w+15
    const int l0 = CST * (cidx + 1);

    __shared__ __align__(16) float eh[CST * 52 + 16]; // exp2(emit/ln2), stride 52
    __shared__ int ml[CST];

    for (int i = lane; i < CST * 52 + 16; i += 64) eh[i] = 1.0f;  // pad-safe
    __syncthreads();

    const float* fbc = feats + ((size_t)b * LEN + l0) * TAGS;
    {
      const float4* fv = (const float4*)fbc;
      for (int i = lane; i < (CST * TAGS) / 4; i += 64) {
        const float4 v4 = fv[i];
        const int g = i * 4;
#pragma unroll
        for (int e = 0; e < 4; ++e) {
          const int gg = g + e;
          const int row = gg / TAGS;
          const int col = gg - row * TAGS;
          const float val = (e == 0) ? v4.x : (e == 1) ? v4.y : (e == 2) ? v4.z : v4.w;
          eh[row * 52 + col] = EXP2F(val * INV_LN2);
        }
      }
      for (int i = lane; i < CST; i += 64) ml[i] = mask[b * LEN + l0 + i];
    }

    // Constant A-frags: E2^T, sigma: slot (c2,q,j) -> row 32c2+16(j>>2)+4q+2((j>>1)&1)+(j&1)
    U8 Afr[4][2];
#pragma unroll
    for (int tm = 0; tm < 4; ++tm)
#pragma unroll
      for (int c2 = 0; c2 < 2; ++c2)
#pragma unroll
        for (int rr = 0; rr < 4; ++rr) {
          const int m = 16 * tm + n;
          const int kr = 32 * c2 + 16 * (rr >> 1) + 4 * q + 2 * (rr & 1);
          const float e0 = (m < TAGS && kr < TAGS)
              ? EXP2F(trans[kr * TAGS + m] * INV_LN2) : 0.0f;
          const float e1 = (m < TAGS && kr + 1 < TAGS)
              ? EXP2F(trans[(kr + 1) * TAGS + m] * INV_LN2) : 0.0f;
          Afr[tm][c2].i[rr] = bfpack(e0, e1);
        }

    __syncthreads();

    // Y = basis columns: d[tm][e] = Y[16tm+4q+e][16w+n] = (tm==w && 4q+e==n)
    f32x4 d[4];
#pragma unroll
    for (int tm = 0; tm < 4; ++tm)
#pragma unroll
      for (int e = 0; e < 4; ++e)
        d[tm][e] = (tm == w && (4 * q + e) == n) ? 1.0f : 0.0f;

    float S = 0.0f;

    for (int l = 0; l < CST; ++l) {
      if (ml[l] > 0) {
        // Own diagonal pivot Y[16w][16w]: tm=w, q=0,e=0,n=0 -> lane 0 of d[w][0]
        float pvt = d[0][0];
        pvt = (w == 1) ? d[1][0] : pvt;
        pvt = (w == 2) ? d[2][0] : pvt;
        pvt = (w == 3) ? d[3][0] : pvt;
        const float cc = readlane_f(pvt, 0);          // > 0
        const float rv = RCPF(cc);

        // Lane-local repack: B slot pairs from own d (sigma trick, R11-verified)
        U8 B0, B1;
        B0.i[0] = bfpack(d[0][0], d[0][1]);
        B0.i[1] = bfpack(d[0][2], d[0][3]);
        B0.i[2] = bfpack(d[1][0], d[1][1]);
        B0.i[3] = bfpack(d[1][2], d[1][3]);
        B1.i[0] = bfpack(d[2][0], d[2][1]);
        B1.i[1] = bfpack(d[2][2], d[2][3]);
        B1.i[2] = bfpack(d[3][0], d[3][1]);
        B1.i[3] = bfpack(d[3][2], d[3][3]);

        // 8 MFMAs (4 tm x 2 K-chunks), then row-scale by eh*rv
#pragma unroll
        for (int tm = 0; tm < 4; ++tm) {
          f32x4 acc = __builtin_amdgcn_mfma_f32_16x16x32_bf16(
              Afr[tm][0].v, B0.v, zero4, 0, 0, 0);
          acc = __builtin_amdgcn_mfma_f32_16x16x32_bf16(
              Afr[tm][1].v, B1.v, acc, 0, 0, 0);
          const f32x4 er = *(const f32x4*)&eh[l * 52 + 16 * tm + 4 * q];
#pragma unroll
          for (int e = 0; e < 4; ++e) d[tm][e] = acc[e] * (er[e] * rv);
        }
        S += LOG2F(cc);
      }
    }

    // Store slab col-major: T~[row][col] at col*64+row.
    float* tw = ws + WS_T(b, cidx) + (16 * w + n) * 64;
#pragma unroll
    for (int tm = 0; tm < 4; ++tm)
      *(f32x4*)&tw[16 * tm + 4 * q] = d[tm];
    if (lane == 0) ws[WS_SC4(b, cidx) + w] = S;
  }
}

__global__ __launch_bounds__(64) void crf_combine_kernel(
    const float* __restrict__ feats,   // (B, L, T)
    const float* __restrict__ trans,   // (T, T)
    const int*   __restrict__ tags,    // (B, L)
    const int*   __restrict__ mask,    // (B, L)
    const float* __restrict__ ws,
    float*       __restrict__ out)     // (B,)
{
  const int b = blockIdx.x;
  const int lane = threadIdx.x;

  float x = ws[WS_U(b) + lane];                       // pads 0
  float Ssum = 0.0f;

  for (int c = 0; c < NCH; ++c) {
    // Per-slab scale correction: true T col j = T~ col j * 2^{S_w(j)}
    const float sw = ws[WS_SC4(b, c) + (lane >> 4)];
    float m1 = fmaxf(sw, __shfl_xor(sw, 16, 64));
    const float smax = fmaxf(m1, __shfl_xor(m1, 32, 64));
    x *= EXP2F(sw - smax);

    const float* Tb = ws + WS_T(b, c) + lane;
    float a0 = 0.0f, a1 = 0.0f, a2 = 0.0f, a3 = 0.0f;
#pragma unroll
    for (int i = 0; i < 64; i += 4) {
      a0 = fmaf(Tb[(i + 0) * 64], readlane_f(x, i + 0), a0);
      a1 = fmaf(Tb[(i + 1) * 64], readlane_f(x, i + 1), a1);
      a2 = fmaf(Tb[(i + 2) * 64], readlane_f(x, i + 2), a2);
      a3 = fmaf(Tb[(i + 3) * 64], readlane_f(x, i + 3), a3);
    }
    const float acc = (a0 + a1) + (a2 + a3);
    const float cc = readlane_f(acc, 0);              // > 0
    x = acc * RCPF(cc);
    Ssum += smax + LOG2F(cc);
  }

  // dot with w
  float s = x * ws[WS_W(b) + lane];
#pragma unroll
  for (int off = 32; off; off >>= 1) s += __shfl_xor(s, off, 64);

  // gold score
  const float* fb = feats + (size_t)b * (LEN * TAGS);
  const int*   tb = tags + b * LEN;
  const int*   mb = mask + b * LEN;
  float gp = 0.0f;
#pragma unroll
  for (int k = 0; k < 4; ++k) {
    const int p = lane + 64 * k;
    const int tg = tb[p];
    if (mb[p] > 0) {
      float vv = fb[p * TAGS + tg];
      if (p >= 1) vv += trans[tb[p - 1] * TAGS + tg];
      gp += vv;
    }
  }
#pragma unroll
  for (int off = 32; off; off >>= 1) gp += __shfl_xor(gp, off, 64);

  if (lane == 0) {
    const float Sf = ws[WS_SF(b)];
    const float Sb = ws[WS_SB(b)];
    out[b] = LN2 * (Sf + Sb + Ssum + LOG2F(s)) - gp;
  }
}

extern "C" void kernel_launch(void* const* d_in, const int* in_sizes, int n_in,
                              void* d_out, int out_size, void* d_ws, size_t ws_size,
                              hipStream_t stream) {
  const float* feats = (const float*)d_in[0];
  const float* trans = (const float*)d_in[1];
  const int*   tags  = (const int*)d_in[2];
  const int*   mask  = (const int*)d_in[3];
  float* out = (float*)d_out;
  float* ws  = (float*)d_ws;   // ~25.3 MB

  crf_scan_kernel<<<2 * NB + NB * NCH * 4, 64, 0, stream>>>(feats, trans, mask, ws);
  crf_combine_kernel<<<NB, 64, 0, stream>>>(feats, trans, tags, mask, ws, out);
}

// Round 14
// 112.070 us; speedup vs baseline: 1.2436x; 1.2436x over previous
//
#include <hip/hip_runtime.h>
#include <math.h>

// CRF loss: B=256, L=256, T=50.
// R14: VALU-issue-bound middle scan rebalanced.
//   normalizer = v0 . M1..M255 . 1,  M_l = mask_l ? E2*diag(eh_l) : I.
//   One scan kernel, 1792 blocks x 256 threads (4 waves):
//     blocks 0..255    fwd chain (wave 0): u = v0 . M1..M47     [R10-proven]
//     blocks 256..511  bwd chain (wave 0): w = M208..M255 . 1   [R10-proven]
//     blocks 512..1791 middle chunk (b, c=0..4): l0 = 48+32c, 32 steps.
//       4 waves = 4 column slabs (R13-verified independence via sigma repack).
//       eh preloaded ONCE per chunk by all 256 threads (no 4x redundancy).
//   Combine (256 blocks x 64): x=u; 5x (slab-scale, x <- T~_c x); dot w; gold.

#define TAGS 50
#define LEN 256
#define NB 256
#define VST 48
#define NCH 5
#define CST 32
#define INV_LN2 1.4426950408889634f
#define LN2 0.6931471805599453f

typedef __attribute__((ext_vector_type(8))) short bf16x8;
typedef __attribute__((ext_vector_type(4))) float f32x4;

#if __has_builtin(__builtin_amdgcn_exp2f)
#define EXP2F(x) __builtin_amdgcn_exp2f(x)
#else
#define EXP2F(x) exp2f(x)
#endif
#if __has_builtin(__builtin_amdgcn_logf)
#define LOG2F(x) __builtin_amdgcn_logf(x)
#else
#define LOG2F(x) log2f(x)
#endif
#if __has_builtin(__builtin_amdgcn_rcpf)
#define RCPF(x) __builtin_amdgcn_rcpf(x)
#else
#define RCPF(x) (1.0f / (x))
#endif

__device__ __forceinline__ float readlane_f(float v, int srclane) {
  return __builtin_bit_cast(float,
      __builtin_amdgcn_readlane(__builtin_bit_cast(int, v), srclane));
}

__device__ __forceinline__ int bfpack(float lo, float hi) {
  unsigned lb = __builtin_bit_cast(unsigned, lo) + 0x8000u;
  unsigned hb = __builtin_bit_cast(unsigned, hi) + 0x8000u;
#if __has_builtin(__builtin_amdgcn_perm)
  return (int)__builtin_amdgcn_perm(hb, lb, 0x07060302u);
#else
  return (int)((hb & 0xFFFF0000u) | (lb >> 16));
#endif
}

union U8 { int i[4]; bf16x8 v; };

// ws layout (floats)
#define WS_U(b)     ((b) * 64)
#define WS_W(b)     ((NB + (b)) * 64)
#define WS_SF(b)    (2 * NB * 64 + (b))
#define WS_SB(b)    (2 * NB * 64 + NB + (b))
#define WS_SC4(b,c) (2 * NB * 64 + 2 * NB + ((b) * NCH + (c)) * 4)
#define WS_T(b,c)   (2 * NB * 64 + 2 * NB + NB * NCH * 4 + (((b) * NCH + (c)) * 64) * 64)

// shared buffer union: chains need VST*TAGS=2400 f + 48 int; middle 1680 f + 32 int
#define SMEM_F 2400
#define SMEM_I 48

__global__ __launch_bounds__(256) void crf_scan_kernel(
    const float* __restrict__ feats,   // (B, L, T)
    const float* __restrict__ trans,   // (T, T)
    const int*   __restrict__ mask,    // (B, L)
    float*       __restrict__ ws)
{
  const int bid  = blockIdx.x;
  const int tid  = threadIdx.x;
  const int wav  = tid >> 6;
  const int lane = tid & 63;
  const int q    = (tid >> 4) & 3;
  const int n    = tid & 15;
  const f32x4 zero4 = {0.0f, 0.0f, 0.0f, 0.0f};

  __shared__ __align__(16) float smem[SMEM_F + 16];
  __shared__ int smi[SMEM_I];

  if (bid < 2 * NB) {
    // ================= VECTOR CHAINS (R10-proven; wave 0 computes) ==========
    const bool is_fwd = bid < NB;
    const int b = is_fwd ? bid : bid - NB;
    const int base_l = is_fwd ? 0 : (LEN - VST);
    const float* fb = feats + ((size_t)b * LEN + base_l) * TAGS;
    const int*   mb = mask + b * LEN + base_l;

    float* fl = smem;
    {
      const float4* fv = (const float4*)fb;           // 600 float4
      for (int i = tid; i < (VST * TAGS) / 4; i += 256) {
        float4 v4 = fv[i];
        v4.x *= INV_LN2; v4.y *= INV_LN2; v4.z *= INV_LN2; v4.w *= INV_LN2;
        *(float4*)&fl[i * 4] = v4;
      }
      if (tid < VST) smi[tid] = mb[tid];
    }
    __syncthreads();
    if (wav != 0) return;                             // chains are single-wave

    int tcl[4], vld[4];
#pragma unroll
    for (int t = 0; t < 4; ++t) {
      const int tg = n + 16 * t;
      vld[t] = tg < TAGS;
      tcl[t] = vld[t] ? tg : (TAGS - 1);
    }

    U8 Bfr[4][2];
#pragma unroll
    for (int t = 0; t < 4; ++t)
#pragma unroll
      for (int c = 0; c < 2; ++c)
#pragma unroll
        for (int r = 0; r < 4; ++r) {
          const int col = 16 * t + n;
          const int tag0 = 16 * c + 4 * q + r;
          const int tag1 = tag0 + 32;
          float e0 = 0.0f, e1 = 0.0f;
          if (col < TAGS) {
            if (tag0 < TAGS)
              e0 = EXP2F((is_fwd ? trans[tag0 * TAGS + col]
                                 : trans[col * TAGS + tag0]) * INV_LN2);
            if (tag1 < TAGS)
              e1 = EXP2F((is_fwd ? trans[tag1 * TAGS + col]
                                 : trans[col * TAGS + tag1]) * INV_LN2);
          }
          Bfr[t][c].i[r] = bfpack(e0, e1);
        }

    int addr[4];
#pragma unroll
    for (int r = 0; r < 4; ++r) addr[r] = (4 * q + r) * 4;

    float v[4], S;
    if (is_fwd) {
      const float c0 = fl[0];
#pragma unroll
      for (int t = 0; t < 4; ++t) v[t] = vld[t] ? EXP2F(fl[tcl[t]] - c0) : 0.0f;
      S = c0;
      float eh[4];
#pragma unroll
      for (int t = 0; t < 4; ++t) eh[t] = EXP2F(fl[TAGS + tcl[t]]);
      int m_nxt = smi[1];

      for (int l = 1; l < VST; ++l) {
        const int m_cur = m_nxt;
        const int ln = (l + 1 < VST) ? (l + 1) : (VST - 1);
        const int P0 = bfpack(v[0], v[2]);
        const int P1 = bfpack(v[1], v[3]);
        const float cc = readlane_f(v[0], 0);
        const float rr = RCPF(cc);
        U8 A0, A1;
#pragma unroll
        for (int r = 0; r < 4; ++r) {
          A0.i[r] = __builtin_amdgcn_ds_bpermute(addr[r], P0);
          A1.i[r] = __builtin_amdgcn_ds_bpermute(addr[r], P1);
        }
        f32x4 d0 = __builtin_amdgcn_mfma_f32_16x16x32_bf16(A0.v, Bfr[0][0].v, zero4, 0, 0, 0);
        f32x4 d1 = __builtin_amdgcn_mfma_f32_16x16x32_bf16(A0.v, Bfr[1][0].v, zero4, 0, 0, 0);
        f32x4 d2 = __builtin_amdgcn_mfma_f32_16x16x32_bf16(A0.v, Bfr[2][0].v, zero4, 0, 0, 0);
        f32x4 d3 = __builtin_amdgcn_mfma_f32_16x16x32_bf16(A0.v, Bfr[3][0].v, zero4, 0, 0, 0);
        f32x4 g0 = __builtin_amdgcn_mfma_f32_16x16x32_bf16(A1.v, Bfr[0][1].v, zero4, 0, 0, 0);
        f32x4 g1 = __builtin_amdgcn_mfma_f32_16x16x32_bf16(A1.v, Bfr[1][1].v, zero4, 0, 0, 0);
        f32x4 g2 = __builtin_amdgcn_mfma_f32_16x16x32_bf16(A1.v, Bfr[2][1].v, zero4, 0, 0, 0);
        f32x4 g3 = __builtin_amdgcn_mfma_f32_16x16x32_bf16(A1.v, Bfr[3][1].v, zero4, 0, 0, 0);
        float ehn[4];
#pragma unroll
        for (int t = 0; t < 4; ++t) ehn[t] = fl[ln * TAGS + tcl[t]];
        const int m_n2 = smi[ln];
        v[0] = ((m_cur > 0) ? (d0[0] + g0[0]) * eh[0] : v[0]) * rr;
        v[1] = ((m_cur > 0) ? (d1[0] + g1[0]) * eh[1] : v[1]) * rr;
        v[2] = ((m_cur > 0) ? (d2[0] + g2[0]) * eh[2] : v[2]) * rr;
        v[3] = ((m_cur > 0) ? (d3[0] + g3[0]) * eh[3] : v[3]) * rr;
        S += LOG2F(cc);
#pragma unroll
        for (int t = 0; t < 4; ++t) eh[t] = EXP2F(ehn[t]);
        m_nxt = m_n2;
      }
      if (lane < 16) {
#pragma unroll
        for (int t = 0; t < 4; ++t) ws[WS_U(b) + n + 16 * t] = v[t];
      }
      if (lane == 0) ws[WS_SF(b)] = S;
    } else {
#pragma unroll
      for (int t = 0; t < 4; ++t) v[t] = vld[t] ? 1.0f : 0.0f;
      S = 0.0f;
      float eh[4];
#pragma unroll
      for (int t = 0; t < 4; ++t) eh[t] = EXP2F(fl[(VST - 1) * TAGS + tcl[t]]);
      int m_nxt = smi[VST - 1];

      for (int l = VST - 1; l >= 0; --l) {
        const int m_cur = m_nxt;
        const int ln = (l > 0) ? (l - 1) : 0;
        const float x0 = v[0] * eh[0];
        const float x1 = v[1] * eh[1];
        const float x2 = v[2] * eh[2];
        const float x3 = v[3] * eh[3];
        const int P0 = bfpack(x0, x2);
        const int P1 = bfpack(x1, x3);
        const float cc = readlane_f(v[0], 0);
        const float rr = RCPF(cc);
        U8 A0, A1;
#pragma unroll
        for (int r = 0; r < 4; ++r) {
          A0.i[r] = __builtin_amdgcn_ds_bpermute(addr[r], P0);
          A1.i[r] = __builtin_amdgcn_ds_bpermute(addr[r], P1);
        }
        f32x4 d0 = __builtin_amdgcn_mfma_f32_16x16x32_bf16(A0.v, Bfr[0][0].v, zero4, 0, 0, 0);
        f32x4 d1 = __builtin_amdgcn_mfma_f32_16x16x32_bf16(A0.v, Bfr[1][0].v, zero4, 0, 0, 0);
        f32x4 d2 = __builtin_amdgcn_mfma_f32_16x16x32_bf16(A0.v, Bfr[2][0].v, zero4, 0, 0, 0);
        f32x4 d3 = __builtin_amdgcn_mfma_f32_16x16x32_bf16(A0.v, Bfr[3][0].v, zero4, 0, 0, 0);
        f32x4 g0 = __builtin_amdgcn_mfma_f32_16x16x32_bf16(A1.v, Bfr[0][1].v, zero4, 0, 0, 0);
        f32x4 g1 = __builtin_amdgcn_mfma_f32_16x16x32_bf16(A1.v, Bfr[1][1].v, zero4, 0, 0, 0);
        f32x4 g2 = __builtin_amdgcn_mfma_f32_16x16x32_bf16(A1.v, Bfr[2][1].v, zero4, 0, 0, 0);
        f32x4 g3 = __builtin_amdgcn_mfma_f32_16x16x32_bf16(A1.v, Bfr[3][1].v, zero4, 0, 0, 0);
        float ehn[4];
#pragma unroll
        for (int t = 0; t < 4; ++t) ehn[t] = fl[ln * TAGS + tcl[t]];
        const int m_n2 = smi[ln];
        v[0] = ((m_cur > 0) ? (d0[0] + g0[0]) : v[0]) * rr;
        v[1] = ((m_cur > 0) ? (d1[0] + g1[0]) : v[1]) * rr;
        v[2] = ((m_cur > 0) ? (d2[0] + g2[0]) : v[2]) * rr;
        v[3] = ((m_cur > 0) ? (d3[0] + g3[0]) : v[3]) * rr;
        S += LOG2F(cc);
#pragma unroll
        for (int t = 0; t < 4; ++t) eh[t] = EXP2F(ehn[t]);
        m_nxt = m_n2;
      }
      if (lane < 16) {
#pragma unroll
        for (int t = 0; t < 4; ++t) ws[WS_W(b) + n + 16 * t] = v[t];
      }
      if (lane == 0) ws[WS_SB(b)] = S;
    }
    return;
  }

  // ============== MIDDLE CHUNKS: 4 waves = 4 column slabs =================
  {
    const int i2 = bid - 2 * NB;
    const int b = i2 / NCH;
    const int cidx = i2 - b * NCH;                    // 0..4
    const int l0 = VST + CST * cidx;                  // 48 + 32c
    const int w = wav;                                // this wave's column slab

    float* eh = smem;                                 // stride 52, exp2'd
    // init (pad cols 50/51 + tail stay 1.0 -> finite, killed by zero A rows)
    for (int i = tid; i < SMEM_F + 16; i += 256) eh[i] = 1.0f;
    __syncthreads();

    const float* fbc = feats + ((size_t)b * LEN + l0) * TAGS;
    {
      const float4* fv = (const float4*)fbc;          // 400 float4
      for (int i = tid; i < (CST * TAGS) / 4; i += 256) {
        const float4 v4 = fv[i];
        const int g = i * 4;
#pragma unroll
        for (int e = 0; e < 4; ++e) {
          const int gg = g + e;
          const int row = gg / TAGS;
          const int col = gg - row * TAGS;
          const float val = (e == 0) ? v4.x : (e == 1) ? v4.y : (e == 2) ? v4.z : v4.w;
          eh[row * 52 + col] = EXP2F(val * INV_LN2);
        }
      }
      if (tid < CST) smi[tid] = mask[b * LEN + l0 + tid];
    }

    // Constant A-frags: E2^T, sigma slot (c2,q,j) -> row 32c2+16(j>>2)+4q+2((j>>1)&1)+(j&1)
    U8 Afr[4][2];
#pragma unroll
    for (int tm = 0; tm < 4; ++tm)
#pragma unroll
      for (int c2 = 0; c2 < 2; ++c2)
#pragma unroll
        for (int rr = 0; rr < 4; ++rr) {
          const int m = 16 * tm + n;
          const int kr = 32 * c2 + 16 * (rr >> 1) + 4 * q + 2 * (rr & 1);
          const float e0 = (m < TAGS && kr < TAGS)
              ? EXP2F(trans[kr * TAGS + m] * INV_LN2) : 0.0f;
          const float e1 = (m < TAGS && kr + 1 < TAGS)
              ? EXP2F(trans[(kr + 1) * TAGS + m] * INV_LN2) : 0.0f;
          Afr[tm][c2].i[rr] = bfpack(e0, e1);
        }

    __syncthreads();

    // Y = basis columns of slab w: d[tm][e] = Y[16tm+4q+e][16w+n]
    f32x4 d[4];
#pragma unroll
    for (int tm = 0; tm < 4; ++tm)
#pragma unroll
      for (int e = 0; e < 4; ++e)
        d[tm][e] = (tm == w && (4 * q + e) == n) ? 1.0f : 0.0f;

    float S = 0.0f;

    for (int l = 0; l < CST; ++l) {
      if (smi[l] > 0) {
        // pivot Y[16w][16w] -> d[w][0] at (q=0,n=0) = lane 0 of this wave
        float pvt = d[0][0];
        pvt = (w == 1) ? d[1][0] : pvt;
        pvt = (w == 2) ? d[2][0] : pvt;
        pvt = (w == 3) ? d[3][0] : pvt;
        const float cc = readlane_f(pvt, 0);          // > 0
        const float rv = RCPF(cc);
        const f32x4 rv4 = {rv, rv, rv, rv};

        // lane-local sigma repack -> B-frags
        U8 B0, B1;
        B0.i[0] = bfpack(d[0][0], d[0][1]);
        B0.i[1] = bfpack(d[0][2], d[0][3]);
        B0.i[2] = bfpack(d[1][0], d[1][1]);
        B0.i[3] = bfpack(d[1][2], d[1][3]);
        B1.i[0] = bfpack(d[2][0], d[2][1]);
        B1.i[1] = bfpack(d[2][2], d[2][3]);
        B1.i[2] = bfpack(d[3][0], d[3][1]);
        B1.i[3] = bfpack(d[3][2], d[3][3]);

        // 8 MFMAs (4 tm x 2 K-chunks), vector scale (v_pk_mul_f32)
#pragma unroll
        for (int tm = 0; tm < 4; ++tm) {
          f32x4 acc = __builtin_amdgcn_mfma_f32_16x16x32_bf16(
              Afr[tm][0].v, B0.v, zero4, 0, 0, 0);
          acc = __builtin_amdgcn_mfma_f32_16x16x32_bf16(
              Afr[tm][1].v, B1.v, acc, 0, 0, 0);
          const f32x4 er = *(const f32x4*)&eh[l * 52 + 16 * tm + 4 * q];
          d[tm] = acc * er * rv4;
        }
        S += LOG2F(cc);
      }
    }

    // Store slab col-major: T~[row][col] at col*64+row.
    float* tw = ws + WS_T(b, cidx) + (16 * w + n) * 64;
#pragma unroll
    for (int tm = 0; tm < 4; ++tm)
      *(f32x4*)&tw[16 * tm + 4 * q] = d[tm];
    if (lane == 0) ws[WS_SC4(b, cidx) + w] = S;
  }
}

__global__ __launch_bounds__(64) void crf_combine_kernel(
    const float* __restrict__ feats,   // (B, L, T)
    const float* __restrict__ trans,   // (T, T)
    const int*   __restrict__ tags,    // (B, L)
    const int*   __restrict__ mask,    // (B, L)
    const float* __restrict__ ws,
    float*       __restrict__ out)     // (B,)
{
  const int b = blockIdx.x;
  const int lane = threadIdx.x;

  float x = ws[WS_U(b) + lane];                       // pads 0
  float Ssum = 0.0f;

  for (int c = 0; c < NCH; ++c) {
    const float sw = ws[WS_SC4(b, c) + (lane >> 4)];
    float m1 = fmaxf(sw, __shfl_xor(sw, 16, 64));
    const float smax = fmaxf(m1, __shfl_xor(m1, 32, 64));
    x *= EXP2F(sw - smax);

    const float* Tb = ws + WS_T(b, c) + lane;
    float a0 = 0.0f, a1 = 0.0f, a2 = 0.0f, a3 = 0.0f;
#pragma unroll
    for (int i = 0; i < 64; i += 4) {
      a0 = fmaf(Tb[(i + 0) * 64], readlane_f(x, i + 0), a0);
      a1 = fmaf(Tb[(i + 1) * 64], readlane_f(x, i + 1), a1);
      a2 = fmaf(Tb[(i + 2) * 64], readlane_f(x, i + 2), a2);
      a3 = fmaf(Tb[(i + 3) * 64], readlane_f(x, i + 3), a3);
    }
    const float acc = (a0 + a1) + (a2 + a3);
    const float cc = readlane_f(acc, 0);              // > 0
    x = acc * RCPF(cc);
    Ssum += smax + LOG2F(cc);
  }

  float s = x * ws[WS_W(b) + lane];
#pragma unroll
  for (int off = 32; off; off >>= 1) s += __shfl_xor(s, off, 64);

  const float* fb = feats + (size_t)b * (LEN * TAGS);
  const int*   tb = tags + b * LEN;
  const int*   mb = mask + b * LEN;
  float gp = 0.0f;
#pragma unroll
  for (int k = 0; k < 4; ++k) {
    const int p = lane + 64 * k;
    const int tg = tb[p];
    if (mb[p] > 0) {
      float vv = fb[p * TAGS + tg];
      if (p >= 1) vv += trans[tb[p - 1] * TAGS + tg];
      gp += vv;
    }
  }
#pragma unroll
  for (int off = 32; off; off >>= 1) gp += __shfl_xor(gp, off, 64);

  if (lane == 0) {
    const float Sf = ws[WS_SF(b)];
    const float Sb = ws[WS_SB(b)];
    out[b] = LN2 * (Sf + Sb + Ssum + LOG2F(s)) - gp;
  }
}

extern "C" void kernel_launch(void* const* d_in, const int* in_sizes, int n_in,
                              void* d_out, int out_size, void* d_ws, size_t ws_size,
                              hipStream_t stream) {
  const float* feats = (const float*)d_in[0];
  const float* trans = (const float*)d_in[1];
  const int*   tags  = (const int*)d_in[2];
  const int*   mask  = (const int*)d_in[3];
  float* out = (float*)d_out;
  float* ws  = (float*)d_ws;   // ~21.2 MB

  crf_scan_kernel<<<2 * NB + NB * NCH, 256, 0, stream>>>(feats, trans, mask, ws);
  crf_combine_kernel<<<NB, 64, 0, stream>>>(feats, trans, tags, mask, ws, out);
}